// Round 1
// baseline (291.729 us; speedup 1.0000x reference)
//
#include <hip/hip_runtime.h>
#include <math.h>

#define CCH 256
#define GG 16
#define CG 16
#define PP 9
#define HH 64
#define WW 64
#define NN 4
#define HP 66
#define WP 66

// workspace layout (in floats)
#define OFF_XNHWC 0ull          // 16384*256      = 4,194,304  (reused as y after conv/gemm consume it)
#define OFF_XPAD  4194304ull    // 4*66*66*256    = 4,460,544
#define OFF_X1    8654848ull    // 16384*256      = 4,194,304
#define OFF_OFFS  12849152ull   // 16384*288      = 4,718,592
#define OFF_MASK  17567744ull   // 16384*144      = 2,359,296
// total = 19,927,040 floats = 79.7 MB

__global__ __launch_bounds__(256) void zero_kernel(float* __restrict__ p, int n) {
    int i = blockIdx.x * 256 + threadIdx.x;
    int stride = gridDim.x * 256;
    for (; i < n; i += stride) p[i] = 0.f;
}

// NCHW (4,256,64,64) -> NHWC (16384, 256)
__global__ __launch_bounds__(256) void transpose_nchw_nhwc(const float* __restrict__ x,
                                                           float* __restrict__ xo) {
    __shared__ float t[32][33];
    int hw0 = blockIdx.x * 32, c0 = blockIdx.y * 32, n = blockIdx.z;
    int tx = threadIdx.x, ty = threadIdx.y;
#pragma unroll
    for (int i = 0; i < 4; i++)
        t[ty + i * 8][tx] = x[(size_t)(n * CCH + c0 + ty + i * 8) * 4096 + hw0 + tx];
    __syncthreads();
#pragma unroll
    for (int i = 0; i < 4; i++)
        xo[(size_t)(n * 4096 + hw0 + ty + i * 8) * CCH + c0 + tx] = t[tx][ty + i * 8];
}

// depthwise 3x3 conv (+bias) + LayerNorm + exact GELU, one block per pixel
__global__ __launch_bounds__(256) void conv_ln_gelu(const float* __restrict__ xn,
                                                    const float* __restrict__ dw_w,
                                                    const float* __restrict__ dw_b,
                                                    const float* __restrict__ ln_g,
                                                    const float* __restrict__ ln_b,
                                                    float* __restrict__ x1) {
    int m = blockIdx.x;
    int n = m >> 12, hw = m & 4095, h = hw >> 6, w = hw & 63;
    int c = threadIdx.x;
    float acc = dw_b[c];
#pragma unroll
    for (int ky = 0; ky < 3; ky++) {
        int hy = h + ky - 1;
        if ((unsigned)hy < 64u) {
#pragma unroll
            for (int kx = 0; kx < 3; kx++) {
                int wx = w + kx - 1;
                if ((unsigned)wx < 64u)
                    acc += xn[(size_t)(n * 4096 + hy * 64 + wx) * CCH + c] * dw_w[c * 9 + ky * 3 + kx];
            }
        }
    }
    __shared__ float sred[4];
    int lane = threadIdx.x & 63, wid = threadIdx.x >> 6;
    float v = acc;
#pragma unroll
    for (int off = 32; off; off >>= 1) v += __shfl_down(v, off);
    if (lane == 0) sred[wid] = v;
    __syncthreads();
    float mean = (sred[0] + sred[1] + sred[2] + sred[3]) * (1.f / 256.f);
    __syncthreads();
    float d = acc - mean;
    v = d * d;
#pragma unroll
    for (int off = 32; off; off >>= 1) v += __shfl_down(v, off);
    if (lane == 0) sred[wid] = v;
    __syncthreads();
    float var = (sred[0] + sred[1] + sred[2] + sred[3]) * (1.f / 256.f);
    float xhat = d / sqrtf(var + 1e-5f);
    float gv = xhat * ln_g[c] + ln_b[c];
    float ge = 0.5f * gv * (1.f + erff(gv * 0.70710678118654752f));
    x1[(size_t)m * CCH + c] = ge;
}

// generic fp32 GEMM: C = A(MxK) @ B(KxN) + bias, epilogue by mode
// mode 0: plain row-major; mode 1: scatter into padded NHWC (66x66); mode 2: scatter to NCHW output
__global__ __launch_bounds__(256) void gemm_bias(const float* __restrict__ A,
                                                 const float* __restrict__ B,
                                                 const float* __restrict__ bias,
                                                 float* __restrict__ Cout,
                                                 int M, int N, int K, int mode) {
    __shared__ float As[16][68];
    __shared__ float Bs[16][64];
    int bm = blockIdx.y * 64, bn = blockIdx.x * 64;
    int tid = threadIdx.x;
    int tx = tid & 15, ty = tid >> 4;
    int arow = tid >> 2, acol = (tid & 3) << 2;
    int brow = tid >> 4, bcol = (tid & 15) << 2;
    float acc[4][4] = {{0.f}};
    for (int k0 = 0; k0 < K; k0 += 16) {
        float4 av = *(const float4*)&A[(size_t)(bm + arow) * K + k0 + acol];
        float4 bv = make_float4(0.f, 0.f, 0.f, 0.f);
        int gc = bn + bcol;
        if (gc < N) bv = *(const float4*)&B[(size_t)(k0 + brow) * N + gc];
        __syncthreads();
        As[acol + 0][arow] = av.x;
        As[acol + 1][arow] = av.y;
        As[acol + 2][arow] = av.z;
        As[acol + 3][arow] = av.w;
        *(float4*)&Bs[brow][bcol] = bv;
        __syncthreads();
#pragma unroll
        for (int k = 0; k < 16; k++) {
            float4 a4 = *(const float4*)&As[k][ty << 2];
            float4 b4 = *(const float4*)&Bs[k][tx << 2];
            acc[0][0] += a4.x * b4.x; acc[0][1] += a4.x * b4.y; acc[0][2] += a4.x * b4.z; acc[0][3] += a4.x * b4.w;
            acc[1][0] += a4.y * b4.x; acc[1][1] += a4.y * b4.y; acc[1][2] += a4.y * b4.z; acc[1][3] += a4.y * b4.w;
            acc[2][0] += a4.z * b4.x; acc[2][1] += a4.z * b4.y; acc[2][2] += a4.z * b4.z; acc[2][3] += a4.z * b4.w;
            acc[3][0] += a4.w * b4.x; acc[3][1] += a4.w * b4.y; acc[3][2] += a4.w * b4.z; acc[3][3] += a4.w * b4.w;
        }
    }
#pragma unroll
    for (int i = 0; i < 4; i++) {
        int m = bm + (ty << 2) + i;
#pragma unroll
        for (int j = 0; j < 4; j++) {
            int col = bn + (tx << 2) + j;
            if (col >= N) continue;
            float val = acc[i][j] + bias[col];
            if (mode == 0) {
                Cout[(size_t)m * N + col] = val;
            } else if (mode == 1) {
                int n = m >> 12, hw = m & 4095, h = hw >> 6, w = hw & 63;
                Cout[(size_t)((n * HP + h + 1) * WP + (w + 1)) * CCH + col] = val;
            } else {
                int n = m >> 12, hw = m & 4095;
                Cout[(size_t)(n * CCH + col) * 4096 + hw] = val;
            }
        }
    }
}

// softmax over P=9 per (pixel, group); layout (m, g, p) contiguous
__global__ __launch_bounds__(256) void softmax_mask(float* __restrict__ mk) {
    int t = blockIdx.x * 256 + threadIdx.x;   // 0 .. 16384*16-1
    float* p = mk + (size_t)t * 9;
    float v[9];
    float mx = -1e30f;
#pragma unroll
    for (int i = 0; i < 9; i++) { v[i] = p[i]; mx = fmaxf(mx, v[i]); }
    float s = 0.f;
#pragma unroll
    for (int i = 0; i < 9; i++) { v[i] = expf(v[i] - mx); s += v[i]; }
    float r = 1.f / s;
#pragma unroll
    for (int i = 0; i < 9; i++) p[i] = v[i] * r;
}

__device__ __forceinline__ void corner_acc(const float* __restrict__ xb, int ix, int iy,
                                           float wt, float acc[16]) {
    if ((unsigned)ix < (unsigned)WP && (unsigned)iy < (unsigned)HP) {
        const float4* vp = (const float4*)(xb + ((size_t)iy * WP + ix) * CCH);
#pragma unroll
        for (int q = 0; q < 4; q++) {
            float4 vv = vp[q];
            acc[q * 4 + 0] += wt * vv.x;
            acc[q * 4 + 1] += wt * vv.y;
            acc[q * 4 + 2] += wt * vv.z;
            acc[q * 4 + 3] += wt * vv.w;
        }
    }
}

// DCNv3 sampling core: one thread per (pixel, group)
__global__ __launch_bounds__(256) void dcn_core(const float* __restrict__ xpad,
                                                const float* __restrict__ offs,
                                                const float* __restrict__ mk,
                                                float* __restrict__ y) {
    int t = blockIdx.x * 256 + threadIdx.x;
    int m = t >> 4, g = t & 15;
    int n = m >> 12, hw = m & 4095, h = hw >> 6, w = hw & 63;
    const float* op = offs + (size_t)m * 288 + g * 18;
    const float* mp = mk + (size_t)t * 9;
    const float* xb = xpad + (size_t)n * (HP * WP * CCH) + g * 16;
    float acc[16] = {0.f};
#pragma unroll
    for (int p = 0; p < 9; p++) {
        int dx = p / 3 - 1, dy = p % 3 - 1;
        float px = (float)(w + 1 + dx) + op[2 * p];
        float py = (float)(h + 1 + dy) + op[2 * p + 1];
        float x0f = floorf(px), y0f = floorf(py);
        float fx = px - x0f, fy = py - y0f;
        int x0 = (int)x0f, y0 = (int)y0f;
        float mval = mp[p];
        float w00 = (1.f - fx) * (1.f - fy) * mval;
        float w01 = fx * (1.f - fy) * mval;
        float w10 = (1.f - fx) * fy * mval;
        float w11 = fx * fy * mval;
        corner_acc(xb, x0,     y0,     w00, acc);
        corner_acc(xb, x0 + 1, y0,     w01, acc);
        corner_acc(xb, x0,     y0 + 1, w10, acc);
        corner_acc(xb, x0 + 1, y0 + 1, w11, acc);
    }
    float4* yo = (float4*)(y + (size_t)m * CCH + g * 16);
#pragma unroll
    for (int q = 0; q < 4; q++)
        yo[q] = make_float4(acc[q * 4 + 0], acc[q * 4 + 1], acc[q * 4 + 2], acc[q * 4 + 3]);
}

extern "C" void kernel_launch(void* const* d_in, const int* in_sizes, int n_in,
                              void* d_out, int out_size, void* d_ws, size_t ws_size,
                              hipStream_t stream) {
    const float* x      = (const float*)d_in[0];
    const float* w_in   = (const float*)d_in[1];
    const float* b_in   = (const float*)d_in[2];
    const float* dw_w   = (const float*)d_in[3];
    const float* dw_b   = (const float*)d_in[4];
    const float* ln_g   = (const float*)d_in[5];
    const float* ln_b   = (const float*)d_in[6];
    const float* w_off  = (const float*)d_in[7];
    const float* b_off  = (const float*)d_in[8];
    const float* w_mask = (const float*)d_in[9];
    const float* b_mask = (const float*)d_in[10];
    const float* w_out  = (const float*)d_in[11];
    const float* b_out  = (const float*)d_in[12];
    float* out = (float*)d_out;
    float* ws  = (float*)d_ws;

    float* xnhwc = ws + OFF_XNHWC;
    float* xpad  = ws + OFF_XPAD;
    float* x1    = ws + OFF_X1;
    float* offs  = ws + OFF_OFFS;
    float* mkb   = ws + OFF_MASK;
    float* y     = xnhwc;   // xnhwc dead after conv_ln_gelu + first gemm

    // 1. zero padded buffer (border must be 0)
    zero_kernel<<<2048, 256, 0, stream>>>(xpad, 4460544);
    // 2. NCHW -> NHWC
    transpose_nchw_nhwc<<<dim3(128, 8, 4), dim3(32, 8), 0, stream>>>(x, xnhwc);
    // 3. input_proj GEMM -> padded layout
    gemm_bias<<<dim3(4, 256), 256, 0, stream>>>(xnhwc, w_in, b_in, xpad, 16384, 256, 256, 1);
    // 4. depthwise conv + LN + GELU
    conv_ln_gelu<<<16384, 256, 0, stream>>>(xnhwc, dw_w, dw_b, ln_g, ln_b, x1);
    // 5. offset / mask GEMMs
    gemm_bias<<<dim3(5, 256), 256, 0, stream>>>(x1, w_off, b_off, offs, 16384, 288, 256, 0);
    gemm_bias<<<dim3(3, 256), 256, 0, stream>>>(x1, w_mask, b_mask, mkb, 16384, 144, 256, 0);
    // 6. softmax over P per (pixel, group)
    softmax_mask<<<1024, 256, 0, stream>>>(mkb);
    // 7. DCNv3 bilinear sampling core
    dcn_core<<<1024, 256, 0, stream>>>(xpad, offs, mkb, y);
    // 8. output_proj GEMM + NCHW scatter
    gemm_bias<<<dim3(4, 256), 256, 0, stream>>>(y, w_out, b_out, out, 16384, 256, 256, 2);
}

// Round 2
// 206.356 us; speedup vs baseline: 1.4137x; 1.4137x over previous
//
#include <hip/hip_runtime.h>
#include <math.h>

#define CCH 256
#define HP 66
#define WP 66

typedef __attribute__((ext_vector_type(8))) short bf16x8;
typedef __attribute__((ext_vector_type(8))) unsigned short u16x8;
typedef __attribute__((ext_vector_type(4))) float f32x4;

__device__ __forceinline__ unsigned short f2bf(float f) {
    unsigned int u = __float_as_uint(f);
    unsigned int r = (u + 0x7fffu + ((u >> 16) & 1u)) >> 16;
    return (unsigned short)r;
}
__device__ __forceinline__ float bf2f(unsigned short h) {
    return __uint_as_float(((unsigned int)h) << 16);
}

// ---- workspace layout (bytes) ----
#define OFF_XNBF   0ull          // 16384*256 bf16 = 8,388,608   (reused as y_bf after conv consumes it)
#define OFF_XPAD   8388608ull    // 4*66*66*256 f32 = 17,842,176
#define OFF_X1BF   26230784ull   // 16384*256 bf16 = 8,388,608
#define OFF_OFFS   34619392ull   // 16384*288 f32  = 18,874,368
#define OFF_MASK   53493760ull   // 16384*144 f32  = 9,437,184
#define OFF_WTIN   62930944ull   // 256*256 bf16   = 131,072
#define OFF_WTOFF  63062016ull   // 288*256 bf16   = 147,456
#define OFF_WTMSK  63209472ull   // 144*256 bf16   = 73,728
#define OFF_WTOUT  63283200ull   // 256*256 bf16   = 131,072
// end = 63,414,272 bytes

__global__ __launch_bounds__(256) void zero_kernel(float* __restrict__ p, int n) {
    int i = blockIdx.x * 256 + threadIdx.x;
    int stride = gridDim.x * 256;
    for (; i < n; i += stride) p[i] = 0.f;
}

// NCHW (4,256,64,64) f32 -> NHWC (16384,256) bf16
__global__ __launch_bounds__(256) void transpose_cvt(const float* __restrict__ x,
                                                     unsigned short* __restrict__ xo) {
    __shared__ float t[32][33];
    int hw0 = blockIdx.x * 32, c0 = blockIdx.y * 32, n = blockIdx.z;
    int tx = threadIdx.x, ty = threadIdx.y;
#pragma unroll
    for (int i = 0; i < 4; i++)
        t[ty + i * 8][tx] = x[(size_t)(n * CCH + c0 + ty + i * 8) * 4096 + hw0 + tx];
    __syncthreads();
#pragma unroll
    for (int i = 0; i < 4; i++)
        xo[(size_t)(n * 4096 + hw0 + ty + i * 8) * CCH + c0 + tx] = f2bf(t[tx][ty + i * 8]);
}

// weight (K x N) f32 -> (N x K) bf16
__global__ __launch_bounds__(256) void wtrans(const float* __restrict__ w,
                                              unsigned short* __restrict__ wt, int K, int N) {
    __shared__ float t[32][33];
    int n0 = blockIdx.x * 32, k0 = blockIdx.y * 32;
    int tx = threadIdx.x, ty = threadIdx.y;
#pragma unroll
    for (int i = 0; i < 4; i++) {
        int k = k0 + ty + i * 8;
        if (k < K && n0 + tx < N) t[ty + i * 8][tx] = w[(size_t)k * N + n0 + tx];
    }
    __syncthreads();
#pragma unroll
    for (int i = 0; i < 4; i++) {
        int n = n0 + ty + i * 8, k = k0 + tx;
        if (n < N && k < K) wt[(size_t)n * K + k] = f2bf(t[tx][ty + i * 8]);
    }
}

// depthwise 3x3 conv (+bias) + LayerNorm + exact GELU, one block per pixel; bf16 in/out
__global__ __launch_bounds__(256) void conv_ln_gelu(const unsigned short* __restrict__ xn,
                                                    const float* __restrict__ dw_w,
                                                    const float* __restrict__ dw_b,
                                                    const float* __restrict__ ln_g,
                                                    const float* __restrict__ ln_b,
                                                    unsigned short* __restrict__ x1) {
    int m = blockIdx.x;
    int n = m >> 12, hw = m & 4095, h = hw >> 6, w = hw & 63;
    int c = threadIdx.x;
    float acc = dw_b[c];
#pragma unroll
    for (int ky = 0; ky < 3; ky++) {
        int hy = h + ky - 1;
        if ((unsigned)hy < 64u) {
#pragma unroll
            for (int kx = 0; kx < 3; kx++) {
                int wx = w + kx - 1;
                if ((unsigned)wx < 64u)
                    acc += bf2f(xn[(size_t)(n * 4096 + hy * 64 + wx) * CCH + c]) * dw_w[c * 9 + ky * 3 + kx];
            }
        }
    }
    __shared__ float sred[4];
    int lane = threadIdx.x & 63, wid = threadIdx.x >> 6;
    float v = acc;
#pragma unroll
    for (int off = 32; off; off >>= 1) v += __shfl_down(v, off);
    if (lane == 0) sred[wid] = v;
    __syncthreads();
    float mean = (sred[0] + sred[1] + sred[2] + sred[3]) * (1.f / 256.f);
    __syncthreads();
    float d = acc - mean;
    v = d * d;
#pragma unroll
    for (int off = 32; off; off >>= 1) v += __shfl_down(v, off);
    if (lane == 0) sred[wid] = v;
    __syncthreads();
    float var = (sred[0] + sred[1] + sred[2] + sred[3]) * (1.f / 256.f);
    float xhat = d / sqrtf(var + 1e-5f);
    float gv = xhat * ln_g[c] + ln_b[c];
    float ge = 0.5f * gv * (1.f + erff(gv * 0.70710678118654752f));
    x1[(size_t)m * CCH + c] = f2bf(ge);
}

// bf16 MFMA GEMM: C = A(MxK bf16) @ Bt(NxK bf16)^T + bias(f32)
// block = 256 threads = 2x2 waves, tile 128x128, wave tile 64x64 (4x4 16x16 frags), no LDS
// mode 0: f32 row-major [M][N]; mode 1: scatter padded NHWC f32; mode 2: scatter NCHW f32
__global__ __launch_bounds__(256) void gemm_mfma(const unsigned short* __restrict__ A,
                                                 const unsigned short* __restrict__ Bt,
                                                 const float* __restrict__ bias,
                                                 float* __restrict__ Cout,
                                                 int M, int N, int K, int mode) {
    int tid = threadIdx.x, wid = tid >> 6, lane = tid & 63;
    int wr = wid >> 1, wc = wid & 1;
    int bm = blockIdx.y * 128, bn = blockIdx.x * 128;
    int row0 = bm + wr * 64, col0 = bn + wc * 64;
    int lr = lane & 15, kg = lane >> 4;   // fragment row/col = lr, k-offset = kg*8
    f32x4 acc[4][4];
#pragma unroll
    for (int i = 0; i < 4; i++)
#pragma unroll
        for (int j = 0; j < 4; j++) acc[i][j] = (f32x4){0.f, 0.f, 0.f, 0.f};

    const unsigned short* Ap = A + (size_t)(row0 + lr) * K + kg * 8;
    const unsigned short* Bp[4];
    bool bok[4];
#pragma unroll
    for (int j = 0; j < 4; j++) {
        int c = col0 + j * 16 + lr;
        bok[j] = (c < N);
        Bp[j] = Bt + (size_t)(bok[j] ? c : 0) * K + kg * 8;
    }
    const bf16x8 bzero = {0, 0, 0, 0, 0, 0, 0, 0};
    for (int k0 = 0; k0 < K; k0 += 32) {
        bf16x8 a[4], b[4];
#pragma unroll
        for (int i = 0; i < 4; i++)
            a[i] = *(const bf16x8*)(Ap + (size_t)i * 16 * K + k0);
#pragma unroll
        for (int j = 0; j < 4; j++)
            b[j] = bok[j] ? *(const bf16x8*)(Bp[j] + k0) : bzero;
#pragma unroll
        for (int i = 0; i < 4; i++)
#pragma unroll
            for (int j = 0; j < 4; j++)
                acc[i][j] = __builtin_amdgcn_mfma_f32_16x16x32_bf16(a[i], b[j], acc[i][j], 0, 0, 0);
    }
#pragma unroll
    for (int i = 0; i < 4; i++) {
#pragma unroll
        for (int j = 0; j < 4; j++) {
            int col = col0 + j * 16 + lr;
            if (col >= N) continue;
            float bi = bias[col];
#pragma unroll
            for (int r = 0; r < 4; r++) {
                int m = row0 + i * 16 + kg * 4 + r;
                float val = acc[i][j][r] + bi;
                if (mode == 0) {
                    Cout[(size_t)m * N + col] = val;
                } else if (mode == 1) {
                    int n = m >> 12, hw = m & 4095, h = hw >> 6, w = hw & 63;
                    Cout[(size_t)((n * HP + h + 1) * WP + (w + 1)) * CCH + col] = val;
                } else {
                    int n = m >> 12, hw = m & 4095;
                    Cout[(size_t)(n * CCH + col) * 4096 + hw] = val;
                }
            }
        }
    }
}

// softmax over P=9 per (pixel, group)
__global__ __launch_bounds__(256) void softmax_mask(float* __restrict__ mk) {
    int t = blockIdx.x * 256 + threadIdx.x;
    float* p = mk + (size_t)t * 9;
    float v[9];
    float mx = -1e30f;
#pragma unroll
    for (int i = 0; i < 9; i++) { v[i] = p[i]; mx = fmaxf(mx, v[i]); }
    float s = 0.f;
#pragma unroll
    for (int i = 0; i < 9; i++) { v[i] = expf(v[i] - mx); s += v[i]; }
    float r = 1.f / s;
#pragma unroll
    for (int i = 0; i < 9; i++) p[i] = v[i] * r;
}

__device__ __forceinline__ void corner_acc(const float* __restrict__ xb, int ix, int iy,
                                           float wt, float acc[16]) {
    if ((unsigned)ix < (unsigned)WP && (unsigned)iy < (unsigned)HP) {
        const float4* vp = (const float4*)(xb + ((size_t)iy * WP + ix) * CCH);
#pragma unroll
        for (int q = 0; q < 4; q++) {
            float4 vv = vp[q];
            acc[q * 4 + 0] += wt * vv.x;
            acc[q * 4 + 1] += wt * vv.y;
            acc[q * 4 + 2] += wt * vv.z;
            acc[q * 4 + 3] += wt * vv.w;
        }
    }
}

// DCNv3 sampling core: one thread per (pixel, group); XCD-swizzled block mapping
__global__ __launch_bounds__(256) void dcn_core(const float* __restrict__ xpad,
                                                const float* __restrict__ offs,
                                                const float* __restrict__ mk,
                                                unsigned short* __restrict__ y) {
    // 1024 blocks: chunk-per-XCD swizzle (1024 % 8 == 0 -> bijective)
    int bid = blockIdx.x;
    int sb = (bid & 7) * 128 + (bid >> 3);
    int t = sb * 256 + threadIdx.x;
    int m = t >> 4, g = t & 15;
    int n = m >> 12, hw = m & 4095, h = hw >> 6, w = hw & 63;
    const float* op = offs + (size_t)m * 288 + g * 18;
    const float* mp = mk + (size_t)(m * 16 + g) * 9;
    const float* xb = xpad + (size_t)n * (HP * WP * CCH) + g * 16;
    float acc[16] = {0.f};
#pragma unroll
    for (int p = 0; p < 9; p++) {
        int dx = p / 3 - 1, dy = p % 3 - 1;
        float px = (float)(w + 1 + dx) + op[2 * p];
        float py = (float)(h + 1 + dy) + op[2 * p + 1];
        float x0f = floorf(px), y0f = floorf(py);
        float fx = px - x0f, fy = py - y0f;
        int x0 = (int)x0f, y0 = (int)y0f;
        float mval = mp[p];
        float w00 = (1.f - fx) * (1.f - fy) * mval;
        float w01 = fx * (1.f - fy) * mval;
        float w10 = (1.f - fx) * fy * mval;
        float w11 = fx * fy * mval;
        corner_acc(xb, x0,     y0,     w00, acc);
        corner_acc(xb, x0 + 1, y0,     w01, acc);
        corner_acc(xb, x0,     y0 + 1, w10, acc);
        corner_acc(xb, x0 + 1, y0 + 1, w11, acc);
    }
    unsigned short* yo = y + (size_t)m * CCH + g * 16;
    u16x8 v0, v1;
#pragma unroll
    for (int q = 0; q < 8; q++) { v0[q] = f2bf(acc[q]); v1[q] = f2bf(acc[8 + q]); }
    *(u16x8*)yo = v0;
    *(u16x8*)(yo + 8) = v1;
}

extern "C" void kernel_launch(void* const* d_in, const int* in_sizes, int n_in,
                              void* d_out, int out_size, void* d_ws, size_t ws_size,
                              hipStream_t stream) {
    const float* x      = (const float*)d_in[0];
    const float* w_in   = (const float*)d_in[1];
    const float* b_in   = (const float*)d_in[2];
    const float* dw_w   = (const float*)d_in[3];
    const float* dw_b   = (const float*)d_in[4];
    const float* ln_g   = (const float*)d_in[5];
    const float* ln_b   = (const float*)d_in[6];
    const float* w_off  = (const float*)d_in[7];
    const float* b_off  = (const float*)d_in[8];
    const float* w_mask = (const float*)d_in[9];
    const float* b_mask = (const float*)d_in[10];
    const float* w_out  = (const float*)d_in[11];
    const float* b_out  = (const float*)d_in[12];
    float* out = (float*)d_out;
    char* ws = (char*)d_ws;

    unsigned short* xnbf  = (unsigned short*)(ws + OFF_XNBF);
    float*          xpad  = (float*)(ws + OFF_XPAD);
    unsigned short* x1bf  = (unsigned short*)(ws + OFF_X1BF);
    float*          offs  = (float*)(ws + OFF_OFFS);
    float*          mkb   = (float*)(ws + OFF_MASK);
    unsigned short* wtin  = (unsigned short*)(ws + OFF_WTIN);
    unsigned short* wtoff = (unsigned short*)(ws + OFF_WTOFF);
    unsigned short* wtmsk = (unsigned short*)(ws + OFF_WTMSK);
    unsigned short* wtout = (unsigned short*)(ws + OFF_WTOUT);
    unsigned short* ybf   = xnbf;   // xnbf dead after conv_ln_gelu + input-proj gemm

    // 1. zero padded buffer (border must stay 0)
    zero_kernel<<<2048, 256, 0, stream>>>(xpad, 4460544);
    // 2. NCHW f32 -> NHWC bf16
    transpose_cvt<<<dim3(128, 8, 4), dim3(32, 8), 0, stream>>>(x, xnbf);
    // 3. weight transposes (KxN f32 -> NxK bf16)
    wtrans<<<dim3(8, 8), dim3(32, 8), 0, stream>>>(w_in,   wtin,  256, 256);
    wtrans<<<dim3(9, 8), dim3(32, 8), 0, stream>>>(w_off,  wtoff, 256, 288);
    wtrans<<<dim3(5, 8), dim3(32, 8), 0, stream>>>(w_mask, wtmsk, 256, 144);
    wtrans<<<dim3(8, 8), dim3(32, 8), 0, stream>>>(w_out,  wtout, 256, 256);
    // 4. input_proj GEMM -> padded NHWC f32
    gemm_mfma<<<dim3(2, 128), 256, 0, stream>>>(xnbf, wtin, b_in, xpad, 16384, 256, 256, 1);
    // 5. depthwise conv + LN + GELU (bf16 in/out)
    conv_ln_gelu<<<16384, 256, 0, stream>>>(xnbf, dw_w, dw_b, ln_g, ln_b, x1bf);
    // 6. offset / mask GEMMs
    gemm_mfma<<<dim3(3, 128), 256, 0, stream>>>(x1bf, wtoff, b_off, offs, 16384, 288, 256, 0);
    gemm_mfma<<<dim3(2, 128), 256, 0, stream>>>(x1bf, wtmsk, b_mask, mkb, 16384, 144, 256, 0);
    // 7. softmax over P per (pixel, group)
    softmax_mask<<<1024, 256, 0, stream>>>(mkb);
    // 8. DCNv3 bilinear sampling core (XCD-swizzled)
    dcn_core<<<1024, 256, 0, stream>>>(xpad, offs, mkb, ybf);
    // 9. output_proj GEMM + NCHW scatter
    gemm_mfma<<<dim3(2, 128), 256, 0, stream>>>(ybf, wtout, b_out, out, 16384, 256, 256, 2);
}

// Round 3
// 175.519 us; speedup vs baseline: 1.6621x; 1.1757x over previous
//
#include <hip/hip_runtime.h>
#include <math.h>

#define CCH 256
#define HP 66
#define WP 66

typedef __attribute__((ext_vector_type(8))) short bf16x8;
typedef __attribute__((ext_vector_type(8))) unsigned short u16x8;
typedef __attribute__((ext_vector_type(4))) float f32x4;

__device__ __forceinline__ unsigned short f2bf(float f) {
    unsigned int u = __float_as_uint(f);
    unsigned int r = (u + 0x7fffu + ((u >> 16) & 1u)) >> 16;
    return (unsigned short)r;
}
__device__ __forceinline__ float bf2f(unsigned short h) {
    return __uint_as_float(((unsigned int)h) << 16);
}

// ---- workspace layout (bytes) ----
#define OFF_XNBF   0ull          // 16384*256 bf16 = 8,388,608  (reused as y_bf later)
#define OFF_XPAD   8388608ull    // 4*66*66*256 bf16 = 8,921,088
#define OFF_X1BF   17309696ull   // 16384*256 bf16 = 8,388,608
#define OFF_OFFS   25698304ull   // 16384*288 bf16 = 9,437,184
#define OFF_MASK   35135488ull   // 16384*144 bf16 = 4,718,592
#define OFF_WTIN   39854080ull   // 256*256 bf16   = 131,072
#define OFF_WTOFF  39985152ull   // 288*256 bf16   = 147,456
#define OFF_WTMSK  40132608ull   // 144*256 bf16   = 73,728
#define OFF_WTOUT  40206336ull   // 256*256 bf16   = 131,072
// end = 40,337,408 bytes

__global__ __launch_bounds__(256) void zero_kernel(unsigned int* __restrict__ p, int n) {
    int i = blockIdx.x * 256 + threadIdx.x;
    int stride = gridDim.x * 256;
    for (; i < n; i += stride) p[i] = 0u;
}

// NCHW (4,256,64,64) f32 -> NHWC (16384,256) bf16
__global__ __launch_bounds__(256) void transpose_cvt(const float* __restrict__ x,
                                                     unsigned short* __restrict__ xo) {
    __shared__ float t[32][33];
    int hw0 = blockIdx.x * 32, c0 = blockIdx.y * 32, n = blockIdx.z;
    int tx = threadIdx.x, ty = threadIdx.y;
#pragma unroll
    for (int i = 0; i < 4; i++)
        t[ty + i * 8][tx] = x[(size_t)(n * CCH + c0 + ty + i * 8) * 4096 + hw0 + tx];
    __syncthreads();
#pragma unroll
    for (int i = 0; i < 4; i++)
        xo[(size_t)(n * 4096 + hw0 + ty + i * 8) * CCH + c0 + tx] = f2bf(t[tx][ty + i * 8]);
}

// weight (K x N) f32 -> (N x K) bf16
__global__ __launch_bounds__(256) void wtrans(const float* __restrict__ w,
                                              unsigned short* __restrict__ wt, int K, int N) {
    __shared__ float t[32][33];
    int n0 = blockIdx.x * 32, k0 = blockIdx.y * 32;
    int tx = threadIdx.x, ty = threadIdx.y;
#pragma unroll
    for (int i = 0; i < 4; i++) {
        int k = k0 + ty + i * 8;
        if (k < K && n0 + tx < N) t[ty + i * 8][tx] = w[(size_t)k * N + n0 + tx];
    }
    __syncthreads();
#pragma unroll
    for (int i = 0; i < 4; i++) {
        int n = n0 + ty + i * 8, k = k0 + tx;
        if (n < N && k < K) wt[(size_t)n * K + k] = f2bf(t[tx][ty + i * 8]);
    }
}

// depthwise 3x3 conv (+bias) + LayerNorm + exact GELU, one block per pixel; bf16 in/out
__global__ __launch_bounds__(256) void conv_ln_gelu(const unsigned short* __restrict__ xn,
                                                    const float* __restrict__ dw_w,
                                                    const float* __restrict__ dw_b,
                                                    const float* __restrict__ ln_g,
                                                    const float* __restrict__ ln_b,
                                                    unsigned short* __restrict__ x1) {
    int m = blockIdx.x;
    int n = m >> 12, hw = m & 4095, h = hw >> 6, w = hw & 63;
    int c = threadIdx.x;
    float acc = dw_b[c];
#pragma unroll
    for (int ky = 0; ky < 3; ky++) {
        int hy = h + ky - 1;
        if ((unsigned)hy < 64u) {
#pragma unroll
            for (int kx = 0; kx < 3; kx++) {
                int wx = w + kx - 1;
                if ((unsigned)wx < 64u)
                    acc += bf2f(xn[(size_t)(n * 4096 + hy * 64 + wx) * CCH + c]) * dw_w[c * 9 + ky * 3 + kx];
            }
        }
    }
    __shared__ float sred[4];
    int lane = threadIdx.x & 63, wid = threadIdx.x >> 6;
    float v = acc;
#pragma unroll
    for (int off = 32; off; off >>= 1) v += __shfl_down(v, off);
    if (lane == 0) sred[wid] = v;
    __syncthreads();
    float mean = (sred[0] + sred[1] + sred[2] + sred[3]) * (1.f / 256.f);
    __syncthreads();
    float d = acc - mean;
    v = d * d;
#pragma unroll
    for (int off = 32; off; off >>= 1) v += __shfl_down(v, off);
    if (lane == 0) sred[wid] = v;
    __syncthreads();
    float var = (sred[0] + sred[1] + sred[2] + sred[3]) * (1.f / 256.f);
    float xhat = d / sqrtf(var + 1e-5f);
    float gv = xhat * ln_g[c] + ln_b[c];
    float ge = 0.5f * gv * (1.f + erff(gv * 0.70710678118654752f));
    x1[(size_t)m * CCH + c] = f2bf(ge);
}

// bf16 MFMA GEMM: C = A(MxK bf16) @ Bt(NxK bf16)^T + bias(f32)
// 256 thr = 2x2 waves, tile 128x128, wave 64x64 (4x4 16x16x32 frags), no LDS
// mode 0: f32 row-major; 1: bf16 scatter padded NHWC; 2: f32 scatter NCHW; 3: bf16 row-major
__global__ __launch_bounds__(256) void gemm_mfma(const unsigned short* __restrict__ A,
                                                 const unsigned short* __restrict__ Bt,
                                                 const float* __restrict__ bias,
                                                 void* __restrict__ Cout,
                                                 int M, int N, int K, int mode) {
    int tid = threadIdx.x, wid = tid >> 6, lane = tid & 63;
    int wr = wid >> 1, wc = wid & 1;
    int bm = blockIdx.y * 128, bn = blockIdx.x * 128;
    int row0 = bm + wr * 64, col0 = bn + wc * 64;
    int lr = lane & 15, kg = lane >> 4;
    f32x4 acc[4][4];
#pragma unroll
    for (int i = 0; i < 4; i++)
#pragma unroll
        for (int j = 0; j < 4; j++) acc[i][j] = (f32x4){0.f, 0.f, 0.f, 0.f};

    const unsigned short* Ap = A + (size_t)(row0 + lr) * K + kg * 8;
    const unsigned short* Bp[4];
    bool bok[4];
#pragma unroll
    for (int j = 0; j < 4; j++) {
        int c = col0 + j * 16 + lr;
        bok[j] = (c < N);
        Bp[j] = Bt + (size_t)(bok[j] ? c : 0) * K + kg * 8;
    }
    const bf16x8 bzero = {0, 0, 0, 0, 0, 0, 0, 0};
    for (int k0 = 0; k0 < K; k0 += 32) {
        bf16x8 a[4], b[4];
#pragma unroll
        for (int i = 0; i < 4; i++)
            a[i] = *(const bf16x8*)(Ap + (size_t)i * 16 * K + k0);
#pragma unroll
        for (int j = 0; j < 4; j++)
            b[j] = bok[j] ? *(const bf16x8*)(Bp[j] + k0) : bzero;
#pragma unroll
        for (int i = 0; i < 4; i++)
#pragma unroll
            for (int j = 0; j < 4; j++)
                acc[i][j] = __builtin_amdgcn_mfma_f32_16x16x32_bf16(a[i], b[j], acc[i][j], 0, 0, 0);
    }
#pragma unroll
    for (int i = 0; i < 4; i++) {
#pragma unroll
        for (int j = 0; j < 4; j++) {
            int col = col0 + j * 16 + lr;
            if (col >= N) continue;
            float bi = bias[col];
#pragma unroll
            for (int r = 0; r < 4; r++) {
                int m = row0 + i * 16 + kg * 4 + r;
                float val = acc[i][j][r] + bi;
                if (mode == 0) {
                    ((float*)Cout)[(size_t)m * N + col] = val;
                } else if (mode == 1) {
                    int n = m >> 12, hw = m & 4095, h = hw >> 6, w = hw & 63;
                    ((unsigned short*)Cout)[(size_t)((n * HP + h + 1) * WP + (w + 1)) * CCH + col] = f2bf(val);
                } else if (mode == 2) {
                    int n = m >> 12, hw = m & 4095;
                    ((float*)Cout)[(size_t)(n * CCH + col) * 4096 + hw] = val;
                } else {
                    ((unsigned short*)Cout)[(size_t)m * N + col] = f2bf(val);
                }
            }
        }
    }
}

__device__ __forceinline__ void corner_acc8(const unsigned short* __restrict__ xb, int ix, int iy,
                                            float wt, float acc[8]) {
    if ((unsigned)ix < (unsigned)WP && (unsigned)iy < (unsigned)HP) {
        u16x8 v = *(const u16x8*)(xb + ((size_t)iy * WP + ix) * CCH);
#pragma unroll
        for (int q = 0; q < 8; q++) acc[q] += wt * bf2f(v[q]);
    }
}

// DCNv3 core + fused mask softmax: one thread per (pixel, group, channel-half)
// 2048 blocks, XCD chunk swizzle (2048 % 8 == 0 -> bijective)
__global__ __launch_bounds__(256) void dcn_core(const unsigned short* __restrict__ xpad,
                                                const unsigned short* __restrict__ offs,
                                                const unsigned short* __restrict__ mk,
                                                unsigned short* __restrict__ y) {
    int bid = blockIdx.x;
    int sb = (bid & 7) * 256 + (bid >> 3);
    int t = sb * 256 + threadIdx.x;          // 0 .. 524287
    int half = t & 1, g = (t >> 1) & 15, m = t >> 5;
    int n = m >> 12, hw = m & 4095, h = hw >> 6, w = hw & 63;
    const unsigned int* op32 = (const unsigned int*)(offs + (size_t)m * 288 + g * 18);
    const unsigned short* mp = mk + (size_t)(m * 16 + g) * 9;
    const unsigned short* xb = xpad + (size_t)n * (HP * WP * CCH) + g * 16 + half * 8;

    // in-register softmax over the 9 mask logits
    float mv[9];
    float mx = -1e30f;
#pragma unroll
    for (int i = 0; i < 9; i++) { mv[i] = bf2f(mp[i]); mx = fmaxf(mx, mv[i]); }
    float s = 0.f;
#pragma unroll
    for (int i = 0; i < 9; i++) { mv[i] = expf(mv[i] - mx); s += mv[i]; }
    float rs = 1.f / s;

    float acc[8] = {0.f};
#pragma unroll
    for (int p = 0; p < 9; p++) {
        int dx = p / 3 - 1, dy = p % 3 - 1;
        unsigned int pk = op32[p];
        float ox = bf2f((unsigned short)(pk & 0xffffu));
        float oy = bf2f((unsigned short)(pk >> 16));
        float px = (float)(w + 1 + dx) + ox;
        float py = (float)(h + 1 + dy) + oy;
        float x0f = floorf(px), y0f = floorf(py);
        float fx = px - x0f, fy = py - y0f;
        int x0 = (int)x0f, y0 = (int)y0f;
        float mval = mv[p] * rs;
        float w00 = (1.f - fx) * (1.f - fy) * mval;
        float w01 = fx * (1.f - fy) * mval;
        float w10 = (1.f - fx) * fy * mval;
        float w11 = fx * fy * mval;
        corner_acc8(xb, x0,     y0,     w00, acc);
        corner_acc8(xb, x0 + 1, y0,     w01, acc);
        corner_acc8(xb, x0,     y0 + 1, w10, acc);
        corner_acc8(xb, x0 + 1, y0 + 1, w11, acc);
    }
    u16x8 v;
#pragma unroll
    for (int q = 0; q < 8; q++) v[q] = f2bf(acc[q]);
    *(u16x8*)(y + (size_t)m * CCH + g * 16 + half * 8) = v;
}

extern "C" void kernel_launch(void* const* d_in, const int* in_sizes, int n_in,
                              void* d_out, int out_size, void* d_ws, size_t ws_size,
                              hipStream_t stream) {
    const float* x      = (const float*)d_in[0];
    const float* w_in   = (const float*)d_in[1];
    const float* b_in   = (const float*)d_in[2];
    const float* dw_w   = (const float*)d_in[3];
    const float* dw_b   = (const float*)d_in[4];
    const float* ln_g   = (const float*)d_in[5];
    const float* ln_b   = (const float*)d_in[6];
    const float* w_off  = (const float*)d_in[7];
    const float* b_off  = (const float*)d_in[8];
    const float* w_mask = (const float*)d_in[9];
    const float* b_mask = (const float*)d_in[10];
    const float* w_out  = (const float*)d_in[11];
    const float* b_out  = (const float*)d_in[12];
    float* out = (float*)d_out;
    char* ws = (char*)d_ws;

    unsigned short* xnbf  = (unsigned short*)(ws + OFF_XNBF);
    unsigned short* xpad  = (unsigned short*)(ws + OFF_XPAD);
    unsigned short* x1bf  = (unsigned short*)(ws + OFF_X1BF);
    unsigned short* offs  = (unsigned short*)(ws + OFF_OFFS);
    unsigned short* mkb   = (unsigned short*)(ws + OFF_MASK);
    unsigned short* wtin  = (unsigned short*)(ws + OFF_WTIN);
    unsigned short* wtoff = (unsigned short*)(ws + OFF_WTOFF);
    unsigned short* wtmsk = (unsigned short*)(ws + OFF_WTMSK);
    unsigned short* wtout = (unsigned short*)(ws + OFF_WTOUT);
    unsigned short* ybf   = xnbf;   // xnbf dead after conv_ln_gelu + input-proj gemm

    // 1. zero padded bf16 buffer (border must stay 0)
    zero_kernel<<<2048, 256, 0, stream>>>((unsigned int*)xpad, 2230272);
    // 2. NCHW f32 -> NHWC bf16
    transpose_cvt<<<dim3(128, 8, 4), dim3(32, 8), 0, stream>>>(x, xnbf);
    // 3. weight transposes (KxN f32 -> NxK bf16)
    wtrans<<<dim3(8, 8), dim3(32, 8), 0, stream>>>(w_in,   wtin,  256, 256);
    wtrans<<<dim3(9, 8), dim3(32, 8), 0, stream>>>(w_off,  wtoff, 256, 288);
    wtrans<<<dim3(5, 8), dim3(32, 8), 0, stream>>>(w_mask, wtmsk, 256, 144);
    wtrans<<<dim3(8, 8), dim3(32, 8), 0, stream>>>(w_out,  wtout, 256, 256);
    // 4. input_proj GEMM -> padded NHWC bf16
    gemm_mfma<<<dim3(2, 128), 256, 0, stream>>>(xnbf, wtin, b_in, xpad, 16384, 256, 256, 1);
    // 5. depthwise conv + LN + GELU (bf16 in/out)
    conv_ln_gelu<<<16384, 256, 0, stream>>>(xnbf, dw_w, dw_b, ln_g, ln_b, x1bf);
    // 6. offset / mask GEMMs (bf16 out)
    gemm_mfma<<<dim3(3, 128), 256, 0, stream>>>(x1bf, wtoff, b_off, offs, 16384, 288, 256, 3);
    gemm_mfma<<<dim3(2, 128), 256, 0, stream>>>(x1bf, wtmsk, b_mask, mkb, 16384, 144, 256, 3);
    // 7. DCNv3 core + fused softmax (XCD-swizzled, 2x TLP)
    dcn_core<<<2048, 256, 0, stream>>>(xpad, offs, mkb, ybf);
    // 8. output_proj GEMM + NCHW scatter
    gemm_mfma<<<dim3(2, 128), 256, 0, stream>>>(ybf, wtout, b_out, out, 16384, 256, 256, 2);
}

// Round 4
// 133.988 us; speedup vs baseline: 2.1773x; 1.3100x over previous
//
#include <hip/hip_runtime.h>
#include <math.h>

#define CCH 256
#define HP2 68
#define WP2 68

typedef __attribute__((ext_vector_type(8))) short bf16x8;
typedef __attribute__((ext_vector_type(8))) unsigned short u16x8;
typedef __attribute__((ext_vector_type(4))) float f32x4;

__device__ __forceinline__ unsigned short f2bf(float f) {
    unsigned int u = __float_as_uint(f);
    unsigned int r = (u + 0x7fffu + ((u >> 16) & 1u)) >> 16;
    return (unsigned short)r;
}
__device__ __forceinline__ float bf2f(unsigned short h) {
    return __uint_as_float(((unsigned int)h) << 16);
}

// ---- workspace layout (bytes) ----
#define OFF_XNBF   0ull          // 16384*256 bf16 = 8,388,608  (reused as y_bf after conv+in-gemm)
#define OFF_XPAD   8388608ull    // 4*68*68*256 bf16 = 9,469,952
#define OFF_X1BF   17858560ull   // 16384*256 bf16 = 8,388,608
#define OFF_OFFS   26247168ull   // 16384*288 bf16 = 9,437,184
#define OFF_MASK   35684352ull   // 16384*144 bf16 = 4,718,592
#define OFF_WTIN   40402944ull   // 256*256 bf16   = 131,072
#define OFF_WTOFF  40534016ull   // 288*256 bf16   = 147,456   (wtoff+wtmsk contiguous = 432xK)
#define OFF_WTMSK  40681472ull   // 144*256 bf16   = 73,728
#define OFF_WTOUT  40755200ull   // 256*256 bf16   = 131,072
#define OFF_BOM    40886272ull   // 432 f32        = 1,728
// end = 40,888,000 bytes

// NCHW (4,256,64,64) f32 -> NHWC (16384,256) bf16; also grid-stride zeroes xpad
__global__ __launch_bounds__(256) void transpose_cvt(const float* __restrict__ x,
                                                     unsigned short* __restrict__ xo,
                                                     unsigned int* __restrict__ xpadz) {
    int flat = ((blockIdx.z * gridDim.y + blockIdx.y) * gridDim.x + blockIdx.x);
    int t = threadIdx.y * 32 + threadIdx.x;
    for (unsigned int i = flat * 256 + t; i < 2367488u; i += 4096u * 256u) xpadz[i] = 0u;

    __shared__ float tt[32][33];
    int hw0 = blockIdx.x * 32, c0 = blockIdx.y * 32, n = blockIdx.z;
    int tx = threadIdx.x, ty = threadIdx.y;
#pragma unroll
    for (int i = 0; i < 4; i++)
        tt[ty + i * 8][tx] = x[(size_t)(n * CCH + c0 + ty + i * 8) * 4096 + hw0 + tx];
    __syncthreads();
#pragma unroll
    for (int i = 0; i < 4; i++)
        xo[(size_t)(n * 4096 + hw0 + ty + i * 8) * CCH + c0 + tx] = f2bf(tt[tx][ty + i * 8]);
}

// all 4 weight transposes (KxN f32 -> NxK bf16) + offset/mask bias concat, one dispatch
__global__ __launch_bounds__(256) void wtrans_all(const float* __restrict__ w_in,
                                                  const float* __restrict__ w_off,
                                                  const float* __restrict__ w_mask,
                                                  const float* __restrict__ w_out,
                                                  unsigned short* __restrict__ wtin,
                                                  unsigned short* __restrict__ wtoff,
                                                  unsigned short* __restrict__ wtmsk,
                                                  unsigned short* __restrict__ wtout,
                                                  const float* __restrict__ b_off,
                                                  const float* __restrict__ b_mask,
                                                  float* __restrict__ bias_om) {
    int z = blockIdx.z;
    int tx = threadIdx.x, ty = threadIdx.y;
    if (z == 4) {
        if (blockIdx.y == 0 && blockIdx.x < 2) {
            int i = blockIdx.x * 256 + ty * 32 + tx;
            if (i < 432) bias_om[i] = (i < 288) ? b_off[i] : b_mask[i - 288];
        }
        return;
    }
    const float* w; unsigned short* wt; int N;
    if (z == 0)      { w = w_in;   wt = wtin;  N = 256; }
    else if (z == 1) { w = w_off;  wt = wtoff; N = 288; }
    else if (z == 2) { w = w_mask; wt = wtmsk; N = 144; }
    else             { w = w_out;  wt = wtout; N = 256; }
    const int K = 256;
    int n0 = blockIdx.x * 32, k0 = blockIdx.y * 32;
    if (n0 >= N) return;
    __shared__ float t[32][33];
#pragma unroll
    for (int i = 0; i < 4; i++) {
        int k = k0 + ty + i * 8;
        if (n0 + tx < N) t[ty + i * 8][tx] = w[(size_t)k * N + n0 + tx];
    }
    __syncthreads();
#pragma unroll
    for (int i = 0; i < 4; i++) {
        int n = n0 + ty + i * 8;
        if (n < N) wt[(size_t)n * K + k0 + tx] = f2bf(t[tx][ty + i * 8]);
    }
}

// depthwise 3x3 conv (+bias) + LayerNorm + exact GELU, one block per pixel; bf16 in/out
__global__ __launch_bounds__(256) void conv_ln_gelu(const unsigned short* __restrict__ xn,
                                                    const float* __restrict__ dw_w,
                                                    const float* __restrict__ dw_b,
                                                    const float* __restrict__ ln_g,
                                                    const float* __restrict__ ln_b,
                                                    unsigned short* __restrict__ x1) {
    int m = blockIdx.x;
    int n = m >> 12, hw = m & 4095, h = hw >> 6, w = hw & 63;
    int c = threadIdx.x;
    float acc = dw_b[c];
#pragma unroll
    for (int ky = 0; ky < 3; ky++) {
        int hy = h + ky - 1;
        if ((unsigned)hy < 64u) {
#pragma unroll
            for (int kx = 0; kx < 3; kx++) {
                int wx = w + kx - 1;
                if ((unsigned)wx < 64u)
                    acc += bf2f(xn[(size_t)(n * 4096 + hy * 64 + wx) * CCH + c]) * dw_w[c * 9 + ky * 3 + kx];
            }
        }
    }
    __shared__ float sred[4];
    int lane = threadIdx.x & 63, wid = threadIdx.x >> 6;
    float v = acc;
#pragma unroll
    for (int off = 32; off; off >>= 1) v += __shfl_down(v, off);
    if (lane == 0) sred[wid] = v;
    __syncthreads();
    float mean = (sred[0] + sred[1] + sred[2] + sred[3]) * (1.f / 256.f);
    __syncthreads();
    float d = acc - mean;
    v = d * d;
#pragma unroll
    for (int off = 32; off; off >>= 1) v += __shfl_down(v, off);
    if (lane == 0) sred[wid] = v;
    __syncthreads();
    float var = (sred[0] + sred[1] + sred[2] + sred[3]) * (1.f / 256.f);
    float xhat = d / sqrtf(var + 1e-5f);
    float gv = xhat * ln_g[c] + ln_b[c];
    float ge = 0.5f * gv * (1.f + erff(gv * 0.70710678118654752f));
    x1[(size_t)m * CCH + c] = f2bf(ge);
}

// bf16 MFMA GEMM: C = A(MxK bf16) @ Bt(NxK bf16)^T + bias(f32)
// 256 thr = 2x2 waves, tile 128x128, wave 64x64 (4x4 16x16x32 frags), no LDS
// mode 1: bf16 scatter to padded 68x68 NHWC (rows=pixels, cols=channels)
// mode 4: f32 NCHW, SWAPPED gemm (rows=channels, cols=pixels), bias per row
// mode 5: dual bf16 row-major: col<288 -> C0 (offs, ld 288), else C1 (mask, ld 144)
__global__ __launch_bounds__(256) void gemm_mfma(const unsigned short* __restrict__ A,
                                                 const unsigned short* __restrict__ Bt,
                                                 const float* __restrict__ bias,
                                                 void* __restrict__ C0,
                                                 void* __restrict__ C1,
                                                 int M, int N, int K, int mode) {
    int tid = threadIdx.x, wid = tid >> 6, lane = tid & 63;
    int wr = wid >> 1, wc = wid & 1;
    int bm = blockIdx.y * 128, bn = blockIdx.x * 128;
    int row0 = bm + wr * 64, col0 = bn + wc * 64;
    int lr = lane & 15, kg = lane >> 4;
    f32x4 acc[4][4];
#pragma unroll
    for (int i = 0; i < 4; i++)
#pragma unroll
        for (int j = 0; j < 4; j++) acc[i][j] = (f32x4){0.f, 0.f, 0.f, 0.f};

    const unsigned short* Ap = A + (size_t)(row0 + lr) * K + kg * 8;
    const unsigned short* Bp[4];
    bool bok[4];
#pragma unroll
    for (int j = 0; j < 4; j++) {
        int c = col0 + j * 16 + lr;
        bok[j] = (c < N);
        Bp[j] = Bt + (size_t)(bok[j] ? c : 0) * K + kg * 8;
    }
    const bf16x8 bzero = {0, 0, 0, 0, 0, 0, 0, 0};
    for (int k0 = 0; k0 < K; k0 += 32) {
        bf16x8 a[4], b[4];
#pragma unroll
        for (int i = 0; i < 4; i++)
            a[i] = *(const bf16x8*)(Ap + (size_t)i * 16 * K + k0);
#pragma unroll
        for (int j = 0; j < 4; j++)
            b[j] = bok[j] ? *(const bf16x8*)(Bp[j] + k0) : bzero;
#pragma unroll
        for (int i = 0; i < 4; i++)
#pragma unroll
            for (int j = 0; j < 4; j++)
                acc[i][j] = __builtin_amdgcn_mfma_f32_16x16x32_bf16(a[i], b[j], acc[i][j], 0, 0, 0);
    }
#pragma unroll
    for (int i = 0; i < 4; i++) {
#pragma unroll
        for (int j = 0; j < 4; j++) {
            int col = col0 + j * 16 + lr;
            if (col >= N) continue;
            float bc = (mode == 4) ? 0.f : bias[col];
#pragma unroll
            for (int r = 0; r < 4; r++) {
                int m = row0 + i * 16 + kg * 4 + r;
                float val = acc[i][j][r] + bc;
                if (mode == 1) {
                    int n = m >> 12, hw = m & 4095, h = hw >> 6, w = hw & 63;
                    ((unsigned short*)C0)[(size_t)((n * HP2 + h + 2) * WP2 + (w + 2)) * CCH + col] = f2bf(val);
                } else if (mode == 4) {
                    // m = channel, col = pixel
                    int n = col >> 12, hw = col & 4095;
                    ((float*)C0)[(size_t)(n * CCH + m) * 4096 + hw] = val + bias[m];
                } else {
                    if (col < 288)
                        ((unsigned short*)C0)[(size_t)m * 288 + col] = f2bf(val);
                    else
                        ((unsigned short*)C1)[(size_t)m * 144 + (col - 288)] = f2bf(val);
                }
            }
        }
    }
}

// DCNv3 core + fused mask softmax, branchless via 2-ring pad + coord clamp.
// one thread per (pixel, group, channel-half); 2048 blocks XCD-swizzled
__global__ __launch_bounds__(256) void dcn_core(const unsigned short* __restrict__ xpad,
                                                const unsigned short* __restrict__ offs,
                                                const unsigned short* __restrict__ mk,
                                                unsigned short* __restrict__ y) {
    int bid = blockIdx.x;
    int sb = (bid & 7) * 256 + (bid >> 3);
    int t = sb * 256 + threadIdx.x;          // 0 .. 524287
    int half = t & 1, g = (t >> 1) & 15, m = t >> 5;
    int n = m >> 12, hw = m & 4095, h = hw >> 6, w = hw & 63;
    const unsigned int* op32 = (const unsigned int*)(offs + (size_t)m * 288 + g * 18);
    const unsigned short* mp = mk + ((size_t)m * 16 + g) * 9;
    const unsigned short* xb = xpad + (size_t)n * (HP2 * WP2 * CCH) + g * 16 + half * 8;

    float mv[9];
    float mx = -1e30f;
#pragma unroll
    for (int i = 0; i < 9; i++) { mv[i] = bf2f(mp[i]); mx = fmaxf(mx, mv[i]); }
    float s = 0.f;
#pragma unroll
    for (int i = 0; i < 9; i++) { mv[i] = expf(mv[i] - mx); s += mv[i]; }
    float rs = 1.f / s;

    float acc[8] = {0.f};
#pragma unroll
    for (int p = 0; p < 9; p++) {
        int dx = p / 3 - 1, dy = p % 3 - 1;
        unsigned int pk = op32[p];
        float ox = bf2f((unsigned short)(pk & 0xffffu));
        float oy = bf2f((unsigned short)(pk >> 16));
        // pixel center in 68x68 coords; clamp is EXACT vs reference masking
        float px = fminf(fmaxf((float)(w + 2 + dx) + ox, 0.f), 67.f);
        float py = fminf(fmaxf((float)(h + 2 + dy) + oy, 0.f), 67.f);
        float x0f = floorf(px), y0f = floorf(py);
        float fx = px - x0f, fy = py - y0f;
        int x0 = (int)x0f, y0 = (int)y0f;
        int x1c = min(x0 + 1, 67), y1c = min(y0 + 1, 67);
        float mval = mv[p] * rs;
        float w00 = (1.f - fx) * (1.f - fy) * mval;
        float w01 = fx * (1.f - fy) * mval;
        float w10 = (1.f - fx) * fy * mval;
        float w11 = fx * fy * mval;
        const unsigned short* r0 = xb + (size_t)y0 * (WP2 * CCH);
        const unsigned short* r1 = xb + (size_t)y1c * (WP2 * CCH);
        u16x8 v00 = *(const u16x8*)(r0 + x0 * CCH);
        u16x8 v01 = *(const u16x8*)(r0 + x1c * CCH);
        u16x8 v10 = *(const u16x8*)(r1 + x0 * CCH);
        u16x8 v11 = *(const u16x8*)(r1 + x1c * CCH);
#pragma unroll
        for (int q = 0; q < 8; q++)
            acc[q] += w00 * bf2f(v00[q]) + w01 * bf2f(v01[q])
                    + w10 * bf2f(v10[q]) + w11 * bf2f(v11[q]);
    }
    u16x8 v;
#pragma unroll
    for (int q = 0; q < 8; q++) v[q] = f2bf(acc[q]);
    *(u16x8*)(y + (size_t)m * CCH + g * 16 + half * 8) = v;
}

extern "C" void kernel_launch(void* const* d_in, const int* in_sizes, int n_in,
                              void* d_out, int out_size, void* d_ws, size_t ws_size,
                              hipStream_t stream) {
    const float* x      = (const float*)d_in[0];
    const float* w_in   = (const float*)d_in[1];
    const float* b_in   = (const float*)d_in[2];
    const float* dw_w   = (const float*)d_in[3];
    const float* dw_b   = (const float*)d_in[4];
    const float* ln_g   = (const float*)d_in[5];
    const float* ln_b   = (const float*)d_in[6];
    const float* w_off  = (const float*)d_in[7];
    const float* b_off  = (const float*)d_in[8];
    const float* w_mask = (const float*)d_in[9];
    const float* b_mask = (const float*)d_in[10];
    const float* w_out  = (const float*)d_in[11];
    const float* b_out  = (const float*)d_in[12];
    float* out = (float*)d_out;
    char* ws = (char*)d_ws;

    unsigned short* xnbf  = (unsigned short*)(ws + OFF_XNBF);
    unsigned short* xpad  = (unsigned short*)(ws + OFF_XPAD);
    unsigned short* x1bf  = (unsigned short*)(ws + OFF_X1BF);
    unsigned short* offs  = (unsigned short*)(ws + OFF_OFFS);
    unsigned short* mkb   = (unsigned short*)(ws + OFF_MASK);
    unsigned short* wtin  = (unsigned short*)(ws + OFF_WTIN);
    unsigned short* wtoff = (unsigned short*)(ws + OFF_WTOFF);
    unsigned short* wtmsk = (unsigned short*)(ws + OFF_WTMSK);
    unsigned short* wtout = (unsigned short*)(ws + OFF_WTOUT);
    float*          biasom = (float*)(ws + OFF_BOM);
    unsigned short* ybf   = xnbf;   // xnbf dead after conv_ln_gelu + input-proj gemm

    // 1. NCHW f32 -> NHWC bf16 (+ zero xpad incl. 2-ring border)
    transpose_cvt<<<dim3(128, 8, 4), dim3(32, 8), 0, stream>>>(x, xnbf, (unsigned int*)xpad);
    // 2. all weight transposes + bias concat
    wtrans_all<<<dim3(9, 8, 5), dim3(32, 8), 0, stream>>>(w_in, w_off, w_mask, w_out,
                                                          wtin, wtoff, wtmsk, wtout,
                                                          b_off, b_mask, biasom);
    // 3. input_proj GEMM -> padded 68x68 NHWC bf16
    gemm_mfma<<<dim3(2, 128), 256, 0, stream>>>(xnbf, wtin, b_in, xpad, nullptr, 16384, 256, 256, 1);
    // 4. depthwise conv + LN + GELU
    conv_ln_gelu<<<16384, 256, 0, stream>>>(xnbf, dw_w, dw_b, ln_g, ln_b, x1bf);
    // 5. fused offset+mask GEMM (N=432, dual bf16 out)
    gemm_mfma<<<dim3(4, 128), 256, 0, stream>>>(x1bf, wtoff, biasom, offs, mkb, 16384, 432, 256, 5);
    // 6. DCNv3 core + fused softmax (branchless, XCD-swizzled)
    dcn_core<<<2048, 256, 0, stream>>>(xpad, offs, mkb, ybf);
    // 7. output_proj GEMM, swapped (rows=channels) -> coalesced NCHW f32
    gemm_mfma<<<dim3(128, 2), 256, 0, stream>>>(wtout, ybf, b_out, out, nullptr, 256, 16384, 256, 4);
}

// Round 5
// 112.680 us; speedup vs baseline: 2.5890x; 1.1891x over previous
//
#include <hip/hip_runtime.h>
#include <math.h>

#define CCH 256
#define HP2 68
#define WP2 68

typedef __attribute__((ext_vector_type(8))) short bf16x8;
typedef __attribute__((ext_vector_type(8))) unsigned short u16x8;
typedef __attribute__((ext_vector_type(4))) float f32x4;

__device__ __forceinline__ unsigned short f2bf(float f) {
    unsigned int u = __float_as_uint(f);
    unsigned int r = (u + 0x7fffu + ((u >> 16) & 1u)) >> 16;
    return (unsigned short)r;
}
__device__ __forceinline__ float bf2f(unsigned short h) {
    return __uint_as_float(((unsigned int)h) << 16);
}

// ---- workspace layout (bytes) ----
#define OFF_XNBF   0ull          // 16384*256 bf16 = 8,388,608  (reused as y_bf after conv+in-gemm)
#define OFF_XPAD   8388608ull    // 4*68*68*256 bf16 = 9,469,952
#define OFF_X1BF   17858560ull   // 16384*256 bf16 = 8,388,608
#define OFF_OFFS   26247168ull   // 16384*288 bf16 = 9,437,184
#define OFF_MASK   35684352ull   // 16384*144 bf16 = 4,718,592
#define OFF_WTIN   40402944ull   // 256*256 bf16   = 131,072
#define OFF_WTOFF  40534016ull   // 288*256 bf16   = 147,456   (wtoff+wtmsk contiguous = 432xK)
#define OFF_WTMSK  40681472ull   // 144*256 bf16   = 73,728
#define OFF_WTOUT  40755200ull   // 256*256 bf16   = 131,072
#define OFF_BOM    40886272ull   // 432 f32        = 1,728
#define OFF_DWT    40888064ull   // 9*256 f32      = 9,216  (depthwise w, tap-major)
// end = 40,897,280 bytes

// NCHW (4,256,64,64) f32 -> NHWC (16384,256) bf16; also grid-stride zeroes xpad
__global__ __launch_bounds__(256) void transpose_cvt(const float* __restrict__ x,
                                                     unsigned short* __restrict__ xo,
                                                     unsigned int* __restrict__ xpadz) {
    int flat = ((blockIdx.z * gridDim.y + blockIdx.y) * gridDim.x + blockIdx.x);
    int t = threadIdx.y * 32 + threadIdx.x;
    for (unsigned int i = flat * 256 + t; i < 2367488u; i += 4096u * 256u) xpadz[i] = 0u;

    __shared__ float tt[32][33];
    int hw0 = blockIdx.x * 32, c0 = blockIdx.y * 32, n = blockIdx.z;
    int tx = threadIdx.x, ty = threadIdx.y;
#pragma unroll
    for (int i = 0; i < 4; i++)
        tt[ty + i * 8][tx] = x[(size_t)(n * CCH + c0 + ty + i * 8) * 4096 + hw0 + tx];
    __syncthreads();
#pragma unroll
    for (int i = 0; i < 4; i++)
        xo[(size_t)(n * 4096 + hw0 + ty + i * 8) * CCH + c0 + tx] = f2bf(tt[tx][ty + i * 8]);
}

// all 4 weight transposes (KxN f32 -> NxK bf16) + bias concat + depthwise tap-major
__global__ __launch_bounds__(256) void wtrans_all(const float* __restrict__ w_in,
                                                  const float* __restrict__ w_off,
                                                  const float* __restrict__ w_mask,
                                                  const float* __restrict__ w_out,
                                                  unsigned short* __restrict__ wtin,
                                                  unsigned short* __restrict__ wtoff,
                                                  unsigned short* __restrict__ wtmsk,
                                                  unsigned short* __restrict__ wtout,
                                                  const float* __restrict__ b_off,
                                                  const float* __restrict__ b_mask,
                                                  float* __restrict__ bias_om,
                                                  const float* __restrict__ dw_w,
                                                  float* __restrict__ dwt) {
    int z = blockIdx.z;
    int tx = threadIdx.x, ty = threadIdx.y;
    int t = ty * 32 + tx;
    if (z == 4) {
        if (blockIdx.y == 0 && blockIdx.x < 2) {
            int i = blockIdx.x * 256 + t;
            if (i < 432) bias_om[i] = (i < 288) ? b_off[i] : b_mask[i - 288];
        } else if (blockIdx.y == 1 && blockIdx.x < 9) {
            int tap = blockIdx.x;
            dwt[tap * 256 + t] = dw_w[t * 9 + tap];
        }
        return;
    }
    const float* w; unsigned short* wt; int N;
    if (z == 0)      { w = w_in;   wt = wtin;  N = 256; }
    else if (z == 1) { w = w_off;  wt = wtoff; N = 288; }
    else if (z == 2) { w = w_mask; wt = wtmsk; N = 144; }
    else             { w = w_out;  wt = wtout; N = 256; }
    const int K = 256;
    int n0 = blockIdx.x * 32, k0 = blockIdx.y * 32;
    if (n0 >= N) return;
    __shared__ float tb[32][33];
#pragma unroll
    for (int i = 0; i < 4; i++) {
        int k = k0 + ty + i * 8;
        if (n0 + tx < N) tb[ty + i * 8][tx] = w[(size_t)k * N + n0 + tx];
    }
    __syncthreads();
#pragma unroll
    for (int i = 0; i < 4; i++) {
        int n = n0 + ty + i * 8;
        if (n < N) wt[(size_t)n * K + k0 + tx] = f2bf(tb[tx][ty + i * 8]);
    }
}

// depthwise 3x3 conv (+bias) + LayerNorm + exact GELU
// wave-per-pixel, lane owns 4 channels; zero LDS / zero barriers, one-pass stats
__global__ __launch_bounds__(256) void conv_ln_gelu(const unsigned short* __restrict__ xn,
                                                    const float* __restrict__ dwt,
                                                    const float* __restrict__ dw_b,
                                                    const float* __restrict__ ln_g,
                                                    const float* __restrict__ ln_b,
                                                    unsigned short* __restrict__ x1) {
    int wid = threadIdx.x >> 6, lane = threadIdx.x & 63;
    int m = blockIdx.x * 4 + wid;
    int n = m >> 12, hw = m & 4095, h = hw >> 6, w = hw & 63;
    int c0 = lane << 2;
    float4 bb = *(const float4*)(dw_b + c0);
    float a0 = bb.x, a1 = bb.y, a2 = bb.z, a3 = bb.w;
#pragma unroll
    for (int ky = 0; ky < 3; ky++) {
        int hy = h + ky - 1;
        if ((unsigned)hy >= 64u) continue;
#pragma unroll
        for (int kx = 0; kx < 3; kx++) {
            int wx = w + kx - 1;
            if ((unsigned)wx >= 64u) continue;
            ushort4 xv = *(const ushort4*)(xn + (size_t)(n * 4096 + hy * 64 + wx) * CCH + c0);
            float4 wv = *(const float4*)(dwt + (ky * 3 + kx) * CCH + c0);
            a0 += bf2f(xv.x) * wv.x;
            a1 += bf2f(xv.y) * wv.y;
            a2 += bf2f(xv.z) * wv.z;
            a3 += bf2f(xv.w) * wv.w;
        }
    }
    float s = a0 + a1 + a2 + a3;
    float s2 = a0 * a0 + a1 * a1 + a2 * a2 + a3 * a3;
#pragma unroll
    for (int off = 32; off; off >>= 1) {
        s += __shfl_xor(s, off);
        s2 += __shfl_xor(s2, off);
    }
    float mean = s * (1.f / 256.f);
    float var = s2 * (1.f / 256.f) - mean * mean;
    float rstd = 1.f / sqrtf(var + 1e-5f);
    float4 g4 = *(const float4*)(ln_g + c0);
    float4 b4 = *(const float4*)(ln_b + c0);
    float gv0 = (a0 - mean) * rstd * g4.x + b4.x;
    float gv1 = (a1 - mean) * rstd * g4.y + b4.y;
    float gv2 = (a2 - mean) * rstd * g4.z + b4.z;
    float gv3 = (a3 - mean) * rstd * g4.w + b4.w;
    const float is2 = 0.70710678118654752f;
    ushort4 o;
    o.x = f2bf(0.5f * gv0 * (1.f + erff(gv0 * is2)));
    o.y = f2bf(0.5f * gv1 * (1.f + erff(gv1 * is2)));
    o.z = f2bf(0.5f * gv2 * (1.f + erff(gv2 * is2)));
    o.w = f2bf(0.5f * gv3 * (1.f + erff(gv3 * is2)));
    *(ushort4*)(x1 + (size_t)m * CCH + c0) = o;
}

// bf16 MFMA GEMM: C = A(MxK bf16) @ Bt(NxK bf16)^T + bias(f32)
// 256 thr = 2x2 waves, tile 128x128, wave 64x64 (4x4 16x16x32 frags), no LDS
// mode 1: bf16 scatter to padded 68x68 NHWC (rows=pixels, cols=channels)
// mode 4: f32 NCHW, SWAPPED gemm (rows=channels, cols=pixels), bias per row
// mode 5: dual bf16 row-major: col<288 -> C0 (offs, ld 288), else C1 (mask, ld 144)
__global__ __launch_bounds__(256) void gemm_mfma(const unsigned short* __restrict__ A,
                                                 const unsigned short* __restrict__ Bt,
                                                 const float* __restrict__ bias,
                                                 void* __restrict__ C0,
                                                 void* __restrict__ C1,
                                                 int M, int N, int K, int mode) {
    int tid = threadIdx.x, wid = tid >> 6, lane = tid & 63;
    int wr = wid >> 1, wc = wid & 1;
    int bm = blockIdx.y * 128, bn = blockIdx.x * 128;
    int row0 = bm + wr * 64, col0 = bn + wc * 64;
    int lr = lane & 15, kg = lane >> 4;
    f32x4 acc[4][4];
#pragma unroll
    for (int i = 0; i < 4; i++)
#pragma unroll
        for (int j = 0; j < 4; j++) acc[i][j] = (f32x4){0.f, 0.f, 0.f, 0.f};

    const unsigned short* Ap = A + (size_t)(row0 + lr) * K + kg * 8;
    const unsigned short* Bp[4];
    bool bok[4];
#pragma unroll
    for (int j = 0; j < 4; j++) {
        int c = col0 + j * 16 + lr;
        bok[j] = (c < N);
        Bp[j] = Bt + (size_t)(bok[j] ? c : 0) * K + kg * 8;
    }
    const bf16x8 bzero = {0, 0, 0, 0, 0, 0, 0, 0};
    for (int k0 = 0; k0 < K; k0 += 32) {
        bf16x8 a[4], b[4];
#pragma unroll
        for (int i = 0; i < 4; i++)
            a[i] = *(const bf16x8*)(Ap + (size_t)i * 16 * K + k0);
#pragma unroll
        for (int j = 0; j < 4; j++)
            b[j] = bok[j] ? *(const bf16x8*)(Bp[j] + k0) : bzero;
#pragma unroll
        for (int i = 0; i < 4; i++)
#pragma unroll
            for (int j = 0; j < 4; j++)
                acc[i][j] = __builtin_amdgcn_mfma_f32_16x16x32_bf16(a[i], b[j], acc[i][j], 0, 0, 0);
    }
#pragma unroll
    for (int i = 0; i < 4; i++) {
#pragma unroll
        for (int j = 0; j < 4; j++) {
            int col = col0 + j * 16 + lr;
            if (col >= N) continue;
            float bc = (mode == 4) ? 0.f : bias[col];
#pragma unroll
            for (int r = 0; r < 4; r++) {
                int m = row0 + i * 16 + kg * 4 + r;
                float val = acc[i][j][r] + bc;
                if (mode == 1) {
                    int n = m >> 12, hw = m & 4095, h = hw >> 6, w = hw & 63;
                    ((unsigned short*)C0)[(size_t)((n * HP2 + h + 2) * WP2 + (w + 2)) * CCH + col] = f2bf(val);
                } else if (mode == 4) {
                    // m = channel, col = pixel
                    int n = col >> 12, hw = col & 4095;
                    ((float*)C0)[(size_t)(n * CCH + m) * 4096 + hw] = val + bias[m];
                } else {
                    if (col < 288)
                        ((unsigned short*)C0)[(size_t)m * 288 + col] = f2bf(val);
                    else
                        ((unsigned short*)C1)[(size_t)m * 144 + (col - 288)] = f2bf(val);
                }
            }
        }
    }
}

// DCNv3 core + fused mask softmax, branchless via 2-ring pad + coord clamp.
// one thread per (pixel, group, channel-half); 2048 blocks XCD-swizzled
__global__ __launch_bounds__(256) void dcn_core(const unsigned short* __restrict__ xpad,
                                                const unsigned short* __restrict__ offs,
                                                const unsigned short* __restrict__ mk,
                                                unsigned short* __restrict__ y) {
    int bid = blockIdx.x;
    int sb = (bid & 7) * 256 + (bid >> 3);
    int t = sb * 256 + threadIdx.x;          // 0 .. 524287
    int half = t & 1, g = (t >> 1) & 15, m = t >> 5;
    int n = m >> 12, hw = m & 4095, h = hw >> 6, w = hw & 63;
    const unsigned int* op32 = (const unsigned int*)(offs + (size_t)m * 288 + g * 18);
    const unsigned short* mp = mk + ((size_t)m * 16 + g) * 9;
    const unsigned short* xb = xpad + (size_t)n * (HP2 * WP2 * CCH) + g * 16 + half * 8;

    float mv[9];
    float mx = -1e30f;
#pragma unroll
    for (int i = 0; i < 9; i++) { mv[i] = bf2f(mp[i]); mx = fmaxf(mx, mv[i]); }
    float s = 0.f;
#pragma unroll
    for (int i = 0; i < 9; i++) { mv[i] = expf(mv[i] - mx); s += mv[i]; }
    float rs = 1.f / s;

    float acc[8] = {0.f};
#pragma unroll
    for (int p = 0; p < 9; p++) {
        int dx = p / 3 - 1, dy = p % 3 - 1;
        unsigned int pk = op32[p];
        float ox = bf2f((unsigned short)(pk & 0xffffu));
        float oy = bf2f((unsigned short)(pk >> 16));
        // pixel center in 68x68 coords; clamp is EXACT vs reference masking
        float px = fminf(fmaxf((float)(w + 2 + dx) + ox, 0.f), 67.f);
        float py = fminf(fmaxf((float)(h + 2 + dy) + oy, 0.f), 67.f);
        float x0f = floorf(px), y0f = floorf(py);
        float fx = px - x0f, fy = py - y0f;
        int x0 = (int)x0f, y0 = (int)y0f;
        int x1c = min(x0 + 1, 67), y1c = min(y0 + 1, 67);
        float mval = mv[p] * rs;
        float w00 = (1.f - fx) * (1.f - fy) * mval;
        float w01 = fx * (1.f - fy) * mval;
        float w10 = (1.f - fx) * fy * mval;
        float w11 = fx * fy * mval;
        const unsigned short* r0 = xb + (size_t)y0 * (WP2 * CCH);
        const unsigned short* r1 = xb + (size_t)y1c * (WP2 * CCH);
        u16x8 v00 = *(const u16x8*)(r0 + x0 * CCH);
        u16x8 v01 = *(const u16x8*)(r0 + x1c * CCH);
        u16x8 v10 = *(const u16x8*)(r1 + x0 * CCH);
        u16x8 v11 = *(const u16x8*)(r1 + x1c * CCH);
#pragma unroll
        for (int q = 0; q < 8; q++)
            acc[q] += w00 * bf2f(v00[q]) + w01 * bf2f(v01[q])
                    + w10 * bf2f(v10[q]) + w11 * bf2f(v11[q]);
    }
    u16x8 v;
#pragma unroll
    for (int q = 0; q < 8; q++) v[q] = f2bf(acc[q]);
    *(u16x8*)(y + (size_t)m * CCH + g * 16 + half * 8) = v;
}

extern "C" void kernel_launch(void* const* d_in, const int* in_sizes, int n_in,
                              void* d_out, int out_size, void* d_ws, size_t ws_size,
                              hipStream_t stream) {
    const float* x      = (const float*)d_in[0];
    const float* w_in   = (const float*)d_in[1];
    const float* b_in   = (const float*)d_in[2];
    const float* dw_w   = (const float*)d_in[3];
    const float* dw_b   = (const float*)d_in[4];
    const float* ln_g   = (const float*)d_in[5];
    const float* ln_b   = (const float*)d_in[6];
    const float* w_off  = (const float*)d_in[7];
    const float* b_off  = (const float*)d_in[8];
    const float* w_mask = (const float*)d_in[9];
    const float* b_mask = (const float*)d_in[10];
    const float* w_out  = (const float*)d_in[11];
    const float* b_out  = (const float*)d_in[12];
    float* out = (float*)d_out;
    char* ws = (char*)d_ws;

    unsigned short* xnbf  = (unsigned short*)(ws + OFF_XNBF);
    unsigned short* xpad  = (unsigned short*)(ws + OFF_XPAD);
    unsigned short* x1bf  = (unsigned short*)(ws + OFF_X1BF);
    unsigned short* offs  = (unsigned short*)(ws + OFF_OFFS);
    unsigned short* mkb   = (unsigned short*)(ws + OFF_MASK);
    unsigned short* wtin  = (unsigned short*)(ws + OFF_WTIN);
    unsigned short* wtoff = (unsigned short*)(ws + OFF_WTOFF);
    unsigned short* wtmsk = (unsigned short*)(ws + OFF_WTMSK);
    unsigned short* wtout = (unsigned short*)(ws + OFF_WTOUT);
    float*          biasom = (float*)(ws + OFF_BOM);
    float*          dwt   = (float*)(ws + OFF_DWT);
    unsigned short* ybf   = xnbf;   // xnbf dead after conv_ln_gelu + input-proj gemm

    // 1. NCHW f32 -> NHWC bf16 (+ zero xpad incl. 2-ring border)
    transpose_cvt<<<dim3(128, 8, 4), dim3(32, 8), 0, stream>>>(x, xnbf, (unsigned int*)xpad);
    // 2. all weight transposes + bias concat + depthwise tap-major
    wtrans_all<<<dim3(9, 8, 5), dim3(32, 8), 0, stream>>>(w_in, w_off, w_mask, w_out,
                                                          wtin, wtoff, wtmsk, wtout,
                                                          b_off, b_mask, biasom, dw_w, dwt);
    // 3. input_proj GEMM -> padded 68x68 NHWC bf16
    gemm_mfma<<<dim3(2, 128), 256, 0, stream>>>(xnbf, wtin, b_in, xpad, nullptr, 16384, 256, 256, 1);
    // 4. depthwise conv + LN + GELU (wave-per-pixel, barrier-free)
    conv_ln_gelu<<<4096, 256, 0, stream>>>(xnbf, dwt, dw_b, ln_g, ln_b, x1bf);
    // 5. fused offset+mask GEMM (N=432, dual bf16 out)
    gemm_mfma<<<dim3(4, 128), 256, 0, stream>>>(x1bf, wtoff, biasom, offs, mkb, 16384, 432, 256, 5);
    // 6. DCNv3 core + fused softmax (branchless, XCD-swizzled)
    dcn_core<<<2048, 256, 0, stream>>>(xpad, offs, mkb, ybf);
    // 7. output_proj GEMM, swapped (rows=channels) -> coalesced NCHW f32
    gemm_mfma<<<dim3(128, 2), 256, 0, stream>>>(wtout, ybf, b_out, out, nullptr, 256, 16384, 256, 4);
}